// Round 6
// baseline (749.471 us; speedup 1.0000x reference)
//
#include <hip/hip_runtime.h>
#include <cstddef>
#include <cstdint>

// ---------------------------------------------------------------------------
// WindowAttention + SKConv fused pipeline.
// B=16, H=W=64, DIM=256; groups: (ws=8,sh=4,ch 0..127), (ws=16,sh=8,ch 128..255)
// GH=4 heads per group, GC=32.
// All four big GEMMs (q, kv, sk-proj, final) run as split-bf16 (bf16x3) MFMA.
// Attention is fp32 VALU (conversion target once correctness is established).
//
// Workspace map:
//   [0      , 64 MiB)   qb  : q proj; attention writes IN-PLACE (xatt==qb)
//   [64 MiB , 192 MiB)  kvb : kv proj; featsT aliases after attention
//   [ws_size-1.15MB, ws_size)  tail (ws_size-adaptive placement):
//       q/kv decomposed weights (dead after q/kv GEMMs; part+avb alias them)
//       pw/phw decomposed weights (live through final GEMM)
// ---------------------------------------------------------------------------

typedef __attribute__((ext_vector_type(8))) short short8v;
typedef __attribute__((ext_vector_type(4))) short short4v;
typedef __attribute__((ext_vector_type(4))) float f32x4;

__device__ __forceinline__ float gelu_f(float x) {
  return 0.5f * x * (1.0f + erff(x * 0.7071067811865475f));
}

__device__ __forceinline__ unsigned short f32_to_bf16_rne(float f) {
  unsigned u = __float_as_uint(f);
  unsigned r = 0x7FFFu + ((u >> 16) & 1u);
  return (unsigned short)((u + r) >> 16);
}
__device__ __forceinline__ float bf16_hi_to_f32(unsigned short h) {
  return __uint_as_float(((unsigned)h) << 16);
}

// ---------------------------------------------------------------------------
// Weight decomposition: W[K][N] fp32 -> hiT/loT [N][K] bf16 bits.
// grid = (N/64, K), block = 64.
// ---------------------------------------------------------------------------
__global__ void decomp_w(const float* __restrict__ W,
                         unsigned short* __restrict__ hiT,
                         unsigned short* __restrict__ loT, int N, int K)
{
  const int k = blockIdx.y;
  const int n = blockIdx.x * 64 + threadIdx.x;
  const float f = W[(size_t)k * N + n];
  const unsigned short h = f32_to_bf16_rne(f);
  const unsigned short l = f32_to_bf16_rne(f - bf16_hi_to_f32(h));
  hiT[(size_t)n * K + k] = h;
  loT[(size_t)n * K + k] = l;
}

// ---------------------------------------------------------------------------
// Split-bf16 MFMA GEMM (row-major out): C[M,N] = A[M,256] @ W[256,N] + bias.
// Tile 128x256, BK=32, 512 threads (8 waves 2x4), 64x64 per wave.
// LDS fragment-linear layout -> conflict-free contiguous ds_read_b128.
// A-frag: row=lane&15, k=8*(lane>>4)+i. D: col=lane&15, row=4*(lane>>4)+r.
// ---------------------------------------------------------------------------
__global__ __launch_bounds__(512) void gemm_mfma_bias(
    const float* __restrict__ A, const unsigned short* __restrict__ WhT,
    const unsigned short* __restrict__ WlT, const float* __restrict__ bias,
    float* __restrict__ C, int N)
{
  constexpr int K = 256;
  __shared__ alignas(16) unsigned short Ah[4096];
  __shared__ alignas(16) unsigned short Al[4096];
  __shared__ alignas(16) unsigned short Bh[8192];
  __shared__ alignas(16) unsigned short Bl[8192];

  const int row0 = blockIdx.x * 128;
  const int col0 = blockIdx.y * 256;
  const int tid = threadIdx.x;
  const int lane = tid & 63;
  const int wave = tid >> 6;
  const int wm = wave >> 2, wn = wave & 3;

  f32x4 acc[4][4];
#pragma unroll
  for (int mi = 0; mi < 4; ++mi)
#pragma unroll
    for (int ni = 0; ni < 4; ++ni) {
      f32x4 z = {0.f, 0.f, 0.f, 0.f};
      acc[mi][ni] = z;
    }

  float4 pa[2];
  short8v pbh[2], pbl[2];

#define LOAD_TILE_QKV(k0_)                                                     \
  {                                                                            \
    _Pragma("unroll") for (int p = 0; p < 2; ++p) {                            \
      int flat = p * 512 + tid;                                                \
      int m = flat >> 3, kq = flat & 7;                                        \
      pa[p] = *(const float4*)(A + (size_t)(row0 + m) * K + (k0_) + kq * 4);   \
    }                                                                          \
    _Pragma("unroll") for (int p = 0; p < 2; ++p) {                            \
      int flat = p * 512 + tid;                                                \
      int n = flat >> 2, ko = flat & 3;                                        \
      const size_t off = (size_t)(col0 + n) * 256 + (k0_) + ko * 8;            \
      pbh[p] = *(const short8v*)(WhT + off);                                   \
      pbl[p] = *(const short8v*)(WlT + off);                                   \
    }                                                                          \
  }

  LOAD_TILE_QKV(0);

  for (int ks = 0; ks < 8; ++ks) {
    __syncthreads();
#pragma unroll
    for (int p = 0; p < 2; ++p) {
      int flat = p * 512 + tid;
      int m = flat >> 3, kq = flat & 7;
      float fx[4] = {pa[p].x, pa[p].y, pa[p].z, pa[p].w};
      unsigned short h[4], l[4];
#pragma unroll
      for (int j = 0; j < 4; ++j) {
        h[j] = f32_to_bf16_rne(fx[j]);
        l[j] = f32_to_bf16_rne(fx[j] - bf16_hi_to_f32(h[j]));
      }
      int e4 = (m >> 4) * 512 + (kq >> 1) * 128 + (m & 15) * 8 + (kq & 1) * 4;
      short4v hv = {(short)h[0], (short)h[1], (short)h[2], (short)h[3]};
      short4v lv = {(short)l[0], (short)l[1], (short)l[2], (short)l[3]};
      *(short4v*)&Ah[e4] = hv;
      *(short4v*)&Al[e4] = lv;
    }
#pragma unroll
    for (int p = 0; p < 2; ++p) {
      int flat = p * 512 + tid;
      int n = flat >> 2, ko = flat & 3;
      int e = (n >> 4) * 512 + ko * 128 + (n & 15) * 8;
      *(short8v*)&Bh[e] = pbh[p];
      *(short8v*)&Bl[e] = pbl[p];
    }
    __syncthreads();

    if (ks < 7) LOAD_TILE_QKV((ks + 1) * 32);

    short8v ah[4], alo[4], bh[4], blo[4];
#pragma unroll
    for (int mi = 0; mi < 4; ++mi) {
      int base = (wm * 4 + mi) * 512 + lane * 8;
      ah[mi] = *(const short8v*)&Ah[base];
      alo[mi] = *(const short8v*)&Al[base];
    }
#pragma unroll
    for (int ni = 0; ni < 4; ++ni) {
      int base = (wn * 4 + ni) * 512 + lane * 8;
      bh[ni] = *(const short8v*)&Bh[base];
      blo[ni] = *(const short8v*)&Bl[base];
    }
#pragma unroll
    for (int mi = 0; mi < 4; ++mi)
#pragma unroll
      for (int ni = 0; ni < 4; ++ni) {
        acc[mi][ni] = __builtin_amdgcn_mfma_f32_16x16x32_bf16(ah[mi], bh[ni], acc[mi][ni], 0, 0, 0);
        acc[mi][ni] = __builtin_amdgcn_mfma_f32_16x16x32_bf16(ah[mi], blo[ni], acc[mi][ni], 0, 0, 0);
        acc[mi][ni] = __builtin_amdgcn_mfma_f32_16x16x32_bf16(alo[mi], bh[ni], acc[mi][ni], 0, 0, 0);
      }
  }
#undef LOAD_TILE_QKV

#pragma unroll
  for (int mi = 0; mi < 4; ++mi) {
    const int rowb = row0 + wm * 64 + mi * 16 + (lane >> 4) * 4;
#pragma unroll
    for (int ni = 0; ni < 4; ++ni) {
      const int col = col0 + wn * 64 + ni * 16 + (lane & 15);
      const float bv = bias[col];
#pragma unroll
      for (int r = 0; r < 4; ++r)
        C[(size_t)(rowb + r) * N + col] = acc[mi][ni][r] + bv;
    }
  }
}

// ---------------------------------------------------------------------------
// Swapped-orientation MFMA GEMM for SK projection:
//   featsT[b][c][hw] = sum_k pw[k][c] * xatt[hw][k] + pb[c]
// A-operand = pwT hi/lo [256c][256k] (pre-decomposed), B = xatt (converted).
// Block: 128 c x 256 hw, 512 threads, waves 2(c) x 4(hw), 64x64 per wave.
// Also emits deterministic per-(b,rbl) gelu partial sums into part[16][16][256].
// ---------------------------------------------------------------------------
__global__ __launch_bounds__(512) void gemm_mfma_proj(
    const float* __restrict__ Act, const unsigned short* __restrict__ WhT,
    const unsigned short* __restrict__ WlT, const float* __restrict__ bias,
    float* __restrict__ featsT, float* __restrict__ part)
{
  __shared__ alignas(16) unsigned short Wh[4096];
  __shared__ alignas(16) unsigned short Wl[4096];
  __shared__ alignas(16) unsigned short Bh[8192];
  __shared__ alignas(16) unsigned short Bl[8192];
  __shared__ float pgelu[4][128];

  const int hw0 = blockIdx.x * 256;
  const int c0 = blockIdx.y * 128;
  const int b = hw0 >> 12;
  const int hwp0 = hw0 & 4095;
  const int tid = threadIdx.x;
  const int lane = tid & 63;
  const int wave = tid >> 6;
  const int wc = wave >> 2, wh = wave & 3;

  f32x4 acc[4][4];
#pragma unroll
  for (int mi = 0; mi < 4; ++mi)
#pragma unroll
    for (int ni = 0; ni < 4; ++ni) {
      f32x4 z = {0.f, 0.f, 0.f, 0.f};
      acc[mi][ni] = z;
    }

  float4 pact[4];
  short8v pwh, pwl;

#define LOAD_TILE_PROJ(k0_)                                                    \
  {                                                                            \
    _Pragma("unroll") for (int p = 0; p < 4; ++p) {                            \
      int f = p * 512 + tid;                                                   \
      int h = f >> 3, kq = f & 7;                                              \
      pact[p] = *(const float4*)(Act + (size_t)(hw0 + h) * 256 + (k0_) + kq * 4); \
    }                                                                          \
    {                                                                          \
      int c = tid >> 2, ko = tid & 3;                                          \
      const size_t off = (size_t)(c0 + c) * 256 + (k0_) + ko * 8;              \
      pwh = *(const short8v*)(WhT + off);                                      \
      pwl = *(const short8v*)(WlT + off);                                      \
    }                                                                          \
  }

  LOAD_TILE_PROJ(0);

  for (int ks = 0; ks < 8; ++ks) {
    __syncthreads();
    {
      int c = tid >> 2, ko = tid & 3;
      int e = (c >> 4) * 512 + ko * 128 + (c & 15) * 8;
      *(short8v*)&Wh[e] = pwh;
      *(short8v*)&Wl[e] = pwl;
    }
#pragma unroll
    for (int p = 0; p < 4; ++p) {
      int f = p * 512 + tid;
      int h = f >> 3, kq = f & 7;
      float fx[4] = {pact[p].x, pact[p].y, pact[p].z, pact[p].w};
      unsigned short hh[4], ll[4];
#pragma unroll
      for (int j = 0; j < 4; ++j) {
        hh[j] = f32_to_bf16_rne(fx[j]);
        ll[j] = f32_to_bf16_rne(fx[j] - bf16_hi_to_f32(hh[j]));
      }
      int e4 = (h >> 4) * 512 + (kq >> 1) * 128 + (h & 15) * 8 + (kq & 1) * 4;
      short4v hv = {(short)hh[0], (short)hh[1], (short)hh[2], (short)hh[3]};
      short4v lv = {(short)ll[0], (short)ll[1], (short)ll[2], (short)ll[3]};
      *(short4v*)&Bh[e4] = hv;
      *(short4v*)&Bl[e4] = lv;
    }
    __syncthreads();

    if (ks < 7) LOAD_TILE_PROJ((ks + 1) * 32);

    short8v wfh[4], wfl[4], bfh[4], bfl[4];
#pragma unroll
    for (int mi = 0; mi < 4; ++mi) {
      int base = (wc * 4 + mi) * 512 + lane * 8;
      wfh[mi] = *(const short8v*)&Wh[base];
      wfl[mi] = *(const short8v*)&Wl[base];
    }
#pragma unroll
    for (int ni = 0; ni < 4; ++ni) {
      int base = (wh * 4 + ni) * 512 + lane * 8;
      bfh[ni] = *(const short8v*)&Bh[base];
      bfl[ni] = *(const short8v*)&Bl[base];
    }
#pragma unroll
    for (int mi = 0; mi < 4; ++mi)
#pragma unroll
      for (int ni = 0; ni < 4; ++ni) {
        acc[mi][ni] = __builtin_amdgcn_mfma_f32_16x16x32_bf16(wfh[mi], bfh[ni], acc[mi][ni], 0, 0, 0);
        acc[mi][ni] = __builtin_amdgcn_mfma_f32_16x16x32_bf16(wfh[mi], bfl[ni], acc[mi][ni], 0, 0, 0);
        acc[mi][ni] = __builtin_amdgcn_mfma_f32_16x16x32_bf16(wfl[mi], bfh[ni], acc[mi][ni], 0, 0, 0);
      }
  }
#undef LOAD_TILE_PROJ

  float gsum[4][4];
#pragma unroll
  for (int mi = 0; mi < 4; ++mi)
#pragma unroll
    for (int r = 0; r < 4; ++r) gsum[mi][r] = 0.f;

#pragma unroll
  for (int mi = 0; mi < 4; ++mi) {
    const int c = c0 + wc * 64 + mi * 16 + (lane >> 4) * 4;
#pragma unroll
    for (int ni = 0; ni < 4; ++ni) {
      const int hwl = wh * 64 + ni * 16 + (lane & 15);
      const size_t base = ((size_t)b * 256 + c) * 4096 + hwp0 + hwl;
#pragma unroll
      for (int r = 0; r < 4; ++r) {
        const float val = acc[mi][ni][r] + bias[c + r];
        featsT[base + (size_t)r * 4096] = val;
        gsum[mi][r] += gelu_f(val);
      }
    }
  }
#pragma unroll
  for (int mi = 0; mi < 4; ++mi)
#pragma unroll
    for (int r = 0; r < 4; ++r) {
      float s = gsum[mi][r];
      s += __shfl_xor(s, 1);
      s += __shfl_xor(s, 2);
      s += __shfl_xor(s, 4);
      s += __shfl_xor(s, 8);
      gsum[mi][r] = s;
    }
  if ((lane & 15) == 0) {
#pragma unroll
    for (int mi = 0; mi < 4; ++mi)
#pragma unroll
      for (int r = 0; r < 4; ++r)
        pgelu[wh][wc * 64 + mi * 16 + (lane >> 4) * 4 + r] = gsum[mi][r];
  }
  __syncthreads();
  if (tid < 128) {
    const float s = pgelu[0][tid] + pgelu[1][tid] + pgelu[2][tid] + pgelu[3][tid];
    const int rbl = hwp0 >> 8;
    part[((size_t)b * 16 + rbl) * 256 + c0 + tid] = s;
  }
}

// ---------------------------------------------------------------------------
// Swapped-orientation MFMA GEMM for the final head:
//   out[b][c][hw] = featsT[b][c][hw] + phb[c] + sum_ci phw[ci][c] * fv[hw][ci]
//   fv[hw][ci] = xatt[hw][ci]*av[b][ci] + xatt[hw][128+ci]*av[b][128+ci]
// A = phwT hi/lo [256c][128k]; B = fv (built during staging). K=128, 4 chunks.
// ---------------------------------------------------------------------------
__global__ __launch_bounds__(512) void gemm_mfma_final(
    const float* __restrict__ Act, const float* __restrict__ featsT,
    const float* __restrict__ av, const unsigned short* __restrict__ WhT,
    const unsigned short* __restrict__ WlT, const float* __restrict__ bias,
    float* __restrict__ out)
{
  __shared__ alignas(16) unsigned short Wh[4096];
  __shared__ alignas(16) unsigned short Wl[4096];
  __shared__ alignas(16) unsigned short Bh[8192];
  __shared__ alignas(16) unsigned short Bl[8192];
  __shared__ float avs[256];

  const int hw0 = blockIdx.x * 256;
  const int c0 = blockIdx.y * 128;
  const int b = hw0 >> 12;
  const int hwp0 = hw0 & 4095;
  const int tid = threadIdx.x;
  const int lane = tid & 63;
  const int wave = tid >> 6;
  const int wc = wave >> 2, wh = wave & 3;

  if (tid < 256) avs[tid] = av[b * 256 + tid];

  f32x4 acc[4][4];
#pragma unroll
  for (int mi = 0; mi < 4; ++mi)
#pragma unroll
    for (int ni = 0; ni < 4; ++ni) {
      f32x4 z = {0.f, 0.f, 0.f, 0.f};
      acc[mi][ni] = z;
    }

  float4 px[4], py[4];
  short8v pwh, pwl;

#define LOAD_TILE_FIN(k0_)                                                     \
  {                                                                            \
    _Pragma("unroll") for (int p = 0; p < 4; ++p) {                            \
      int f = p * 512 + tid;                                                   \
      int h = f >> 3, kq = f & 7;                                              \
      const float* bp = Act + (size_t)(hw0 + h) * 256 + (k0_) + kq * 4;        \
      px[p] = *(const float4*)bp;                                              \
      py[p] = *(const float4*)(bp + 128);                                      \
    }                                                                          \
    {                                                                          \
      int c = tid >> 2, ko = tid & 3;                                          \
      const size_t off = (size_t)(c0 + c) * 128 + (k0_) + ko * 8;              \
      pwh = *(const short8v*)(WhT + off);                                      \
      pwl = *(const short8v*)(WlT + off);                                      \
    }                                                                          \
  }

  LOAD_TILE_FIN(0);

  for (int ks = 0; ks < 4; ++ks) {
    const int k0 = ks * 32;
    __syncthreads();
    {
      int c = tid >> 2, ko = tid & 3;
      int e = (c >> 4) * 512 + ko * 128 + (c & 15) * 8;
      *(short8v*)&Wh[e] = pwh;
      *(short8v*)&Wl[e] = pwl;
    }
#pragma unroll
    for (int p = 0; p < 4; ++p) {
      int f = p * 512 + tid;
      int h = f >> 3, kq = f & 7;
      const float4 a0 = *(const float4*)(avs + k0 + kq * 4);
      const float4 a1 = *(const float4*)(avs + 128 + k0 + kq * 4);
      float fx[4];
      fx[0] = px[p].x * a0.x + py[p].x * a1.x;
      fx[1] = px[p].y * a0.y + py[p].y * a1.y;
      fx[2] = px[p].z * a0.z + py[p].z * a1.z;
      fx[3] = px[p].w * a0.w + py[p].w * a1.w;
      unsigned short hh[4], ll[4];
#pragma unroll
      for (int j = 0; j < 4; ++j) {
        hh[j] = f32_to_bf16_rne(fx[j]);
        ll[j] = f32_to_bf16_rne(fx[j] - bf16_hi_to_f32(hh[j]));
      }
      int e4 = (h >> 4) * 512 + (kq >> 1) * 128 + (h & 15) * 8 + (kq & 1) * 4;
      short4v hv = {(short)hh[0], (short)hh[1], (short)hh[2], (short)hh[3]};
      short4v lv = {(short)ll[0], (short)ll[1], (short)ll[2], (short)ll[3]};
      *(short4v*)&Bh[e4] = hv;
      *(short4v*)&Bl[e4] = lv;
    }
    __syncthreads();

    if (ks < 3) LOAD_TILE_FIN((ks + 1) * 32);

    short8v wfh[4], wfl[4], bfh[4], bfl[4];
#pragma unroll
    for (int mi = 0; mi < 4; ++mi) {
      int base = (wc * 4 + mi) * 512 + lane * 8;
      wfh[mi] = *(const short8v*)&Wh[base];
      wfl[mi] = *(const short8v*)&Wl[base];
    }
#pragma unroll
    for (int ni = 0; ni < 4; ++ni) {
      int base = (wh * 4 + ni) * 512 + lane * 8;
      bfh[ni] = *(const short8v*)&Bh[base];
      bfl[ni] = *(const short8v*)&Bl[base];
    }
#pragma unroll
    for (int mi = 0; mi < 4; ++mi)
#pragma unroll
      for (int ni = 0; ni < 4; ++ni) {
        acc[mi][ni] = __builtin_amdgcn_mfma_f32_16x16x32_bf16(wfh[mi], bfh[ni], acc[mi][ni], 0, 0, 0);
        acc[mi][ni] = __builtin_amdgcn_mfma_f32_16x16x32_bf16(wfh[mi], bfl[ni], acc[mi][ni], 0, 0, 0);
        acc[mi][ni] = __builtin_amdgcn_mfma_f32_16x16x32_bf16(wfl[mi], bfh[ni], acc[mi][ni], 0, 0, 0);
      }
  }
#undef LOAD_TILE_FIN

#pragma unroll
  for (int mi = 0; mi < 4; ++mi) {
    const int c = c0 + wc * 64 + mi * 16 + (lane >> 4) * 4;
#pragma unroll
    for (int ni = 0; ni < 4; ++ni) {
      const int hwl = wh * 64 + ni * 16 + (lane & 15);
      const size_t base = ((size_t)b * 256 + c) * 4096 + hwp0 + hwl;
#pragma unroll
      for (int r = 0; r < 4; ++r)
        out[base + (size_t)r * 4096] =
            acc[mi][ni][r] + bias[c + r] + featsT[base + (size_t)r * 4096];
    }
  }
}

// ---------------------------------------------------------------------------
// Windowed attention: one workgroup per (window, head), one thread per row.
// Rolled coords inline (roll/unroll cancel at read & write). Bias + shift
// region mask computed inline. Online softmax over chunks of 32.
// IN-PLACE: qio serves as q input AND output (single pointer, no aliasing UB;
// each thread's read-set == write-set; window partition is bijective).
// ---------------------------------------------------------------------------
template <int WS, int SH, int GRP>
__global__ __launch_bounds__(WS * WS) void attn_kernel(
    float* qio, const float* __restrict__ kvbuf, const float* __restrict__ rpb)
{
  constexpr int N = WS * WS;
  constexpr int NW = 64 / WS;
  constexpr int NBIAS = (2 * WS - 1) * (2 * WS - 1);
  constexpr int LOGWS = (WS == 8) ? 3 : 4;

  __shared__ float ks[N][36];
  __shared__ float vs[N][36];
  __shared__ float sbias[NBIAS];
  __shared__ int sreg[N];

  const int head = blockIdx.x & 3;
  const int win = blockIdx.x >> 2;
  const int b = win / (NW * NW);
  const int wl = win % (NW * NW);
  const int wi = wl / NW, wj = wl % NW;
  const int t = threadIdx.x;
  const int ti = t >> LOGWS, tj = t & (WS - 1);
  const int hr = wi * WS + ti, wr = wj * WS + tj;
  const int hg = (hr + SH) & 63, wg = (wr + SH) & 63;
  const int cb = GRP * 128 + head * 32;

  const size_t pos = ((size_t)b * 64 + hg) * 64 + wg;
  float* qp = qio + pos * 256 + cb;
  const float* kp = kvbuf + pos * 512 + cb;
  const float* vp = kp + 256;

  constexpr float scale = 0.17677669529663687f;  // 32^-0.5
  float qreg[32];
#pragma unroll
  for (int d4 = 0; d4 < 8; ++d4) {
    float4 qv = *(const float4*)(qp + d4 * 4);
    qreg[d4 * 4 + 0] = qv.x * scale; qreg[d4 * 4 + 1] = qv.y * scale;
    qreg[d4 * 4 + 2] = qv.z * scale; qreg[d4 * 4 + 3] = qv.w * scale;
    float4 kk4 = *(const float4*)(kp + d4 * 4);
    ks[t][d4 * 4 + 0] = kk4.x; ks[t][d4 * 4 + 1] = kk4.y;
    ks[t][d4 * 4 + 2] = kk4.z; ks[t][d4 * 4 + 3] = kk4.w;
    float4 vv4 = *(const float4*)(vp + d4 * 4);
    vs[t][d4 * 4 + 0] = vv4.x; vs[t][d4 * 4 + 1] = vv4.y;
    vs[t][d4 * 4 + 2] = vv4.z; vs[t][d4 * 4 + 3] = vv4.w;
  }
  for (int i = t; i < NBIAS; i += N) sbias[i] = rpb[i * 4 + head];
  const int rrh = (hr < 64 - WS) ? 0 : ((hr < 64 - SH) ? 1 : 2);
  const int rrw = (wr < 64 - WS) ? 0 : ((wr < 64 - SH) ? 1 : 2);
  const int myreg = rrh * 3 + rrw;
  sreg[t] = myreg;
  __syncthreads();

  float oacc[32];
#pragma unroll
  for (int d = 0; d < 32; ++d) oacc[d] = 0.f;
  float mrun = -1e30f, lrun = 0.f;
  const int tbias = (ti + WS - 1) * (2 * WS - 1) + (tj + WS - 1);

  for (int mc = 0; mc < N; mc += 32) {
    float s[32];
#pragma unroll
    for (int mm = 0; mm < 32; ++mm) {
      const int m = mc + mm;
      const float* kr = &ks[m][0];
      float dot = 0.f;
#pragma unroll
      for (int d4 = 0; d4 < 8; ++d4) {
        float4 k4 = *(const float4*)(kr + d4 * 4);
        dot += qreg[d4 * 4 + 0] * k4.x + qreg[d4 * 4 + 1] * k4.y +
               qreg[d4 * 4 + 2] * k4.z + qreg[d4 * 4 + 3] * k4.w;
      }
      const int mi = m >> LOGWS, mj = m & (WS - 1);
      float bias = sbias[tbias - mi * (2 * WS - 1) - mj];
      float msk = (sreg[m] == myreg) ? 0.f : -100.f;
      s[mm] = dot + bias + msk;
    }
    float mx = mrun;
#pragma unroll
    for (int mm = 0; mm < 32; ++mm) mx = fmaxf(mx, s[mm]);
    const float corr = expf(mrun - mx);
    lrun *= corr;
#pragma unroll
    for (int d = 0; d < 32; ++d) oacc[d] *= corr;
#pragma unroll
    for (int mm = 0; mm < 32; ++mm) {
      const int m = mc + mm;
      const float p = expf(s[mm] - mx);
      lrun += p;
      const float* vr = &vs[m][0];
#pragma unroll
      for (int d4 = 0; d4 < 8; ++d4) {
        float4 v4 = *(const float4*)(vr + d4 * 4);
        oacc[d4 * 4 + 0] += p * v4.x; oacc[d4 * 4 + 1] += p * v4.y;
        oacc[d4 * 4 + 2] += p * v4.z; oacc[d4 * 4 + 3] += p * v4.w;
      }
    }
    mrun = mx;
  }

  const float inv = 1.f / lrun;
#pragma unroll
  for (int d4 = 0; d4 < 8; ++d4) {
    float4 o;
    o.x = oacc[d4 * 4 + 0] * inv; o.y = oacc[d4 * 4 + 1] * inv;
    o.z = oacc[d4 * 4 + 2] * inv; o.w = oacc[d4 * 4 + 3] * inv;
    *(float4*)(qp + d4 * 4) = o;
  }
}

// ---------------------------------------------------------------------------
// SK squeeze-excite MLP (tiny): S = mean over 16 partial blocks, then 2-layer
// MLP + group softmax -> av[b][256].
// ---------------------------------------------------------------------------
__global__ __launch_bounds__(256) void sk_small(
    const float* __restrict__ part, const float* __restrict__ f1w,
    const float* __restrict__ f1b, const float* __restrict__ f2w,
    const float* __restrict__ f2b, float* __restrict__ av)
{
  const int b = blockIdx.x;
  __shared__ float S[256];
  __shared__ float Z[64];
  __shared__ float Araw[256];
  const int tid = threadIdx.x;
  {
    float s = 0.f;
    for (int rb = 0; rb < 16; ++rb) s += part[((size_t)b * 16 + rb) * 256 + tid];
    S[tid] = s * (1.f / 4096.f);
  }
  __syncthreads();
  if (tid < 64) {
    float s = f1b[tid];
    for (int c = 0; c < 256; ++c) s += S[c] * f1w[c * 64 + tid];
    Z[tid] = gelu_f(s);
  }
  __syncthreads();
  {
    float s = f2b[tid];
    for (int j = 0; j < 64; ++j) s += Z[j] * f2w[j * 256 + tid];
    Araw[tid] = s;
  }
  __syncthreads();
  if (tid < 128) {
    float a0 = Araw[tid], a1 = Araw[128 + tid];
    float mx = fmaxf(a0, a1);
    float e0 = expf(a0 - mx), e1 = expf(a1 - mx);
    float inv = 1.f / (e0 + e1);
    av[b * 256 + tid] = e0 * inv;
    av[b * 256 + 128 + tid] = e1 * inv;
  }
}

// ---------------------------------------------------------------------------
extern "C" void kernel_launch(void* const* d_in, const int* in_sizes, int n_in,
                              void* d_out, int out_size, void* d_ws, size_t ws_size,
                              hipStream_t stream)
{
  (void)in_sizes; (void)n_in; (void)out_size;
  const float* x_q   = (const float*)d_in[0];
  const float* x_kv  = (const float*)d_in[1];
  const float* w_q   = (const float*)d_in[2];
  const float* b_q   = (const float*)d_in[3];
  const float* w_kv  = (const float*)d_in[4];
  const float* b_kv  = (const float*)d_in[5];
  const float* rpb0  = (const float*)d_in[6];
  const float* rpb1  = (const float*)d_in[7];
  const float* pw    = (const float*)d_in[8];
  const float* pb    = (const float*)d_in[9];
  const float* f1w   = (const float*)d_in[10];
  const float* f1b   = (const float*)d_in[11];
  const float* f2w   = (const float*)d_in[12];
  const float* f2b   = (const float*)d_in[13];
  const float* phw   = (const float*)d_in[14];
  const float* phb   = (const float*)d_in[15];
  float* out = (float*)d_out;

  float* ws = (float*)d_ws;
  // qb: 16,777,216 f (64 MiB). Attention output written IN-PLACE.
  float* qb  = ws;
  // kvb: 33,554,432 f (128 MiB). Dead after attention; featsT aliases it.
  float* kvb = ws + 16777216;
  float* featsT = kvb;
  float* xatt = qb;

  // Tail placed at the END of the workspace (ws_size-adaptive, 256B-aligned):
  //   wq (131,072 us) + wk (262,144 us) = 786,432 B  [dead after q/kv GEMMs;
  //       part (65,536 f) + avb (4,096 f) = 278,528 B alias them]
  //   pw (131,072 us) + ph (65,536 us)   = 393,216 B  [live through final]
  // Total tail = 1,179,648 B. Requires ws_size >= 192 MiB + ~1.2 MB.
  const size_t tail_bytes = 1179648;
  uintptr_t tail_addr = ((uintptr_t)d_ws + ws_size - tail_bytes) & ~(uintptr_t)255;
  unsigned short* wqh = (unsigned short*)tail_addr;
  unsigned short* wql = wqh + 65536;
  unsigned short* wkh = wql + 65536;
  unsigned short* wkl = wkh + 131072;
  float* part = (float*)tail_addr;      // aliases wqh..wkl after q/kv GEMMs
  float* avb  = part + 65536;
  unsigned short* pwh = wkl + 131072;
  unsigned short* pwl = pwh + 65536;
  unsigned short* phh = pwl + 65536;
  unsigned short* phl = phh + 32768;

  decomp_w<<<dim3(4, 256), 64, 0, stream>>>(w_q, wqh, wql, 256, 256);
  decomp_w<<<dim3(8, 256), 64, 0, stream>>>(w_kv, wkh, wkl, 512, 256);
  decomp_w<<<dim3(4, 256), 64, 0, stream>>>(pw, pwh, pwl, 256, 256);
  decomp_w<<<dim3(4, 128), 64, 0, stream>>>(phw, phh, phl, 256, 128);
  gemm_mfma_bias<<<dim3(512, 1), 512, 0, stream>>>(x_q, wqh, wql, b_q, qb, 256);
  gemm_mfma_bias<<<dim3(512, 2), 512, 0, stream>>>(x_kv, wkh, wkl, b_kv, kvb, 512);
  attn_kernel<8, 4, 0><<<4096, 64, 0, stream>>>(qb, kvb, rpb0);
  attn_kernel<16, 8, 1><<<1024, 256, 0, stream>>>(qb, kvb, rpb1);
  gemm_mfma_proj<<<dim3(256, 2), 512, 0, stream>>>(xatt, pwh, pwl, pb, featsT, part);
  sk_small<<<16, 256, 0, stream>>>(part, f1w, f1b, f2w, f2b, avb);
  gemm_mfma_final<<<dim3(256, 2), 512, 0, stream>>>(xatt, featsT, avb, phh, phl, phb, out);
}

// Round 11
// 708.448 us; speedup vs baseline: 1.0579x; 1.0579x over previous
//
#include <hip/hip_runtime.h>
#include <cstddef>
#include <cstdint>

// ---------------------------------------------------------------------------
// WindowAttention + SKConv fused pipeline.
// B=16, H=W=64, DIM=256; groups: (ws=8,sh=4,ch 0..127), (ws=16,sh=8,ch 128..255)
// GH=4 heads per group, GC=32.
// All four big GEMMs (q, kv, sk-proj, final) run as split-bf16 (bf16x3) MFMA.
// Attention fp32 VALU, chunked K/V staging CHUNK=N/4 (LDS 20.6KB/5.1KB ->
// ws16 ~5 blocks/CU (62%), ws8 HW-capped ~16 blocks (50%)).
//
// Workspace map:
//   [0      , 64 MiB)   qb  : q proj; attention writes IN-PLACE (xatt==qb)
//   [64 MiB , 192 MiB)  kvb : kv proj; featsT aliases after attention
//   [ws_size-1.15MB, ws_size)  tail (ws_size-adaptive placement)
// ---------------------------------------------------------------------------

typedef __attribute__((ext_vector_type(8))) short short8v;
typedef __attribute__((ext_vector_type(4))) short short4v;
typedef __attribute__((ext_vector_type(4))) float f32x4;

__device__ __forceinline__ float gelu_f(float x) {
  return 0.5f * x * (1.0f + erff(x * 0.7071067811865475f));
}

__device__ __forceinline__ unsigned short f32_to_bf16_rne(float f) {
  unsigned u = __float_as_uint(f);
  unsigned r = 0x7FFFu + ((u >> 16) & 1u);
  return (unsigned short)((u + r) >> 16);
}
__device__ __forceinline__ float bf16_hi_to_f32(unsigned short h) {
  return __uint_as_float(((unsigned)h) << 16);
}

// ---------------------------------------------------------------------------
// Weight decomposition: W[K][N] fp32 -> hiT/loT [N][K] bf16 bits.
// ---------------------------------------------------------------------------
__global__ void decomp_w(const float* __restrict__ W,
                         unsigned short* __restrict__ hiT,
                         unsigned short* __restrict__ loT, int N, int K)
{
  const int k = blockIdx.y;
  const int n = blockIdx.x * 64 + threadIdx.x;
  const float f = W[(size_t)k * N + n];
  const unsigned short h = f32_to_bf16_rne(f);
  const unsigned short l = f32_to_bf16_rne(f - bf16_hi_to_f32(h));
  hiT[(size_t)n * K + k] = h;
  loT[(size_t)n * K + k] = l;
}

// ---------------------------------------------------------------------------
// Split-bf16 MFMA GEMM (row-major out): C[M,N] = A[M,256] @ W[256,N] + bias.
// Tile 128x256, BK=32, 512 threads (8 waves 2x4), 64x64 per wave.
// ---------------------------------------------------------------------------
__global__ __launch_bounds__(512) void gemm_mfma_bias(
    const float* __restrict__ A, const unsigned short* __restrict__ WhT,
    const unsigned short* __restrict__ WlT, const float* __restrict__ bias,
    float* __restrict__ C, int N)
{
  constexpr int K = 256;
  __shared__ alignas(16) unsigned short Ah[4096];
  __shared__ alignas(16) unsigned short Al[4096];
  __shared__ alignas(16) unsigned short Bh[8192];
  __shared__ alignas(16) unsigned short Bl[8192];

  const int row0 = blockIdx.x * 128;
  const int col0 = blockIdx.y * 256;
  const int tid = threadIdx.x;
  const int lane = tid & 63;
  const int wave = tid >> 6;
  const int wm = wave >> 2, wn = wave & 3;

  f32x4 acc[4][4];
#pragma unroll
  for (int mi = 0; mi < 4; ++mi)
#pragma unroll
    for (int ni = 0; ni < 4; ++ni) {
      f32x4 z = {0.f, 0.f, 0.f, 0.f};
      acc[mi][ni] = z;
    }

  float4 pa[2];
  short8v pbh[2], pbl[2];

#define LOAD_TILE_QKV(k0_)                                                     \
  {                                                                            \
    _Pragma("unroll") for (int p = 0; p < 2; ++p) {                            \
      int flat = p * 512 + tid;                                                \
      int m = flat >> 3, kq = flat & 7;                                        \
      pa[p] = *(const float4*)(A + (size_t)(row0 + m) * K + (k0_) + kq * 4);   \
    }                                                                          \
    _Pragma("unroll") for (int p = 0; p < 2; ++p) {                            \
      int flat = p * 512 + tid;                                                \
      int n = flat >> 2, ko = flat & 3;                                        \
      const size_t off = (size_t)(col0 + n) * 256 + (k0_) + ko * 8;            \
      pbh[p] = *(const short8v*)(WhT + off);                                   \
      pbl[p] = *(const short8v*)(WlT + off);                                   \
    }                                                                          \
  }

  LOAD_TILE_QKV(0);

  for (int ks = 0; ks < 8; ++ks) {
    __syncthreads();
#pragma unroll
    for (int p = 0; p < 2; ++p) {
      int flat = p * 512 + tid;
      int m = flat >> 3, kq = flat & 7;
      float fx[4] = {pa[p].x, pa[p].y, pa[p].z, pa[p].w};
      unsigned short h[4], l[4];
#pragma unroll
      for (int j = 0; j < 4; ++j) {
        h[j] = f32_to_bf16_rne(fx[j]);
        l[j] = f32_to_bf16_rne(fx[j] - bf16_hi_to_f32(h[j]));
      }
      int e4 = (m >> 4) * 512 + (kq >> 1) * 128 + (m & 15) * 8 + (kq & 1) * 4;
      short4v hv = {(short)h[0], (short)h[1], (short)h[2], (short)h[3]};
      short4v lv = {(short)l[0], (short)l[1], (short)l[2], (short)l[3]};
      *(short4v*)&Ah[e4] = hv;
      *(short4v*)&Al[e4] = lv;
    }
#pragma unroll
    for (int p = 0; p < 2; ++p) {
      int flat = p * 512 + tid;
      int n = flat >> 2, ko = flat & 3;
      int e = (n >> 4) * 512 + ko * 128 + (n & 15) * 8;
      *(short8v*)&Bh[e] = pbh[p];
      *(short8v*)&Bl[e] = pbl[p];
    }
    __syncthreads();

    if (ks < 7) LOAD_TILE_QKV((ks + 1) * 32);

    short8v ah[4], alo[4], bh[4], blo[4];
#pragma unroll
    for (int mi = 0; mi < 4; ++mi) {
      int base = (wm * 4 + mi) * 512 + lane * 8;
      ah[mi] = *(const short8v*)&Ah[base];
      alo[mi] = *(const short8v*)&Al[base];
    }
#pragma unroll
    for (int ni = 0; ni < 4; ++ni) {
      int base = (wn * 4 + ni) * 512 + lane * 8;
      bh[ni] = *(const short8v*)&Bh[base];
      blo[ni] = *(const short8v*)&Bl[base];
    }
#pragma unroll
    for (int mi = 0; mi < 4; ++mi)
#pragma unroll
      for (int ni = 0; ni < 4; ++ni) {
        acc[mi][ni] = __builtin_amdgcn_mfma_f32_16x16x32_bf16(ah[mi], bh[ni], acc[mi][ni], 0, 0, 0);
        acc[mi][ni] = __builtin_amdgcn_mfma_f32_16x16x32_bf16(ah[mi], blo[ni], acc[mi][ni], 0, 0, 0);
        acc[mi][ni] = __builtin_amdgcn_mfma_f32_16x16x32_bf16(alo[mi], bh[ni], acc[mi][ni], 0, 0, 0);
      }
  }
#undef LOAD_TILE_QKV

#pragma unroll
  for (int mi = 0; mi < 4; ++mi) {
    const int rowb = row0 + wm * 64 + mi * 16 + (lane >> 4) * 4;
#pragma unroll
    for (int ni = 0; ni < 4; ++ni) {
      const int col = col0 + wn * 64 + ni * 16 + (lane & 15);
      const float bv = bias[col];
#pragma unroll
      for (int r = 0; r < 4; ++r)
        C[(size_t)(rowb + r) * N + col] = acc[mi][ni][r] + bv;
    }
  }
}

// ---------------------------------------------------------------------------
// Swapped-orientation MFMA GEMM for SK projection (featsT out + gelu partials).
// ---------------------------------------------------------------------------
__global__ __launch_bounds__(512) void gemm_mfma_proj(
    const float* __restrict__ Act, const unsigned short* __restrict__ WhT,
    const unsigned short* __restrict__ WlT, const float* __restrict__ bias,
    float* __restrict__ featsT, float* __restrict__ part)
{
  __shared__ alignas(16) unsigned short Wh[4096];
  __shared__ alignas(16) unsigned short Wl[4096];
  __shared__ alignas(16) unsigned short Bh[8192];
  __shared__ alignas(16) unsigned short Bl[8192];
  __shared__ float pgelu[4][128];

  const int hw0 = blockIdx.x * 256;
  const int c0 = blockIdx.y * 128;
  const int b = hw0 >> 12;
  const int hwp0 = hw0 & 4095;
  const int tid = threadIdx.x;
  const int lane = tid & 63;
  const int wave = tid >> 6;
  const int wc = wave >> 2, wh = wave & 3;

  f32x4 acc[4][4];
#pragma unroll
  for (int mi = 0; mi < 4; ++mi)
#pragma unroll
    for (int ni = 0; ni < 4; ++ni) {
      f32x4 z = {0.f, 0.f, 0.f, 0.f};
      acc[mi][ni] = z;
    }

  float4 pact[4];
  short8v pwh, pwl;

#define LOAD_TILE_PROJ(k0_)                                                    \
  {                                                                            \
    _Pragma("unroll") for (int p = 0; p < 4; ++p) {                            \
      int f = p * 512 + tid;                                                   \
      int h = f >> 3, kq = f & 7;                                              \
      pact[p] = *(const float4*)(Act + (size_t)(hw0 + h) * 256 + (k0_) + kq * 4); \
    }                                                                          \
    {                                                                          \
      int c = tid >> 2, ko = tid & 3;                                          \
      const size_t off = (size_t)(c0 + c) * 256 + (k0_) + ko * 8;              \
      pwh = *(const short8v*)(WhT + off);                                      \
      pwl = *(const short8v*)(WlT + off);                                      \
    }                                                                          \
  }

  LOAD_TILE_PROJ(0);

  for (int ks = 0; ks < 8; ++ks) {
    __syncthreads();
    {
      int c = tid >> 2, ko = tid & 3;
      int e = (c >> 4) * 512 + ko * 128 + (c & 15) * 8;
      *(short8v*)&Wh[e] = pwh;
      *(short8v*)&Wl[e] = pwl;
    }
#pragma unroll
    for (int p = 0; p < 4; ++p) {
      int f = p * 512 + tid;
      int h = f >> 3, kq = f & 7;
      float fx[4] = {pact[p].x, pact[p].y, pact[p].z, pact[p].w};
      unsigned short hh[4], ll[4];
#pragma unroll
      for (int j = 0; j < 4; ++j) {
        hh[j] = f32_to_bf16_rne(fx[j]);
        ll[j] = f32_to_bf16_rne(fx[j] - bf16_hi_to_f32(hh[j]));
      }
      int e4 = (h >> 4) * 512 + (kq >> 1) * 128 + (h & 15) * 8 + (kq & 1) * 4;
      short4v hv = {(short)hh[0], (short)hh[1], (short)hh[2], (short)hh[3]};
      short4v lv = {(short)ll[0], (short)ll[1], (short)ll[2], (short)ll[3]};
      *(short4v*)&Bh[e4] = hv;
      *(short4v*)&Bl[e4] = lv;
    }
    __syncthreads();

    if (ks < 7) LOAD_TILE_PROJ((ks + 1) * 32);

    short8v wfh[4], wfl[4], bfh[4], bfl[4];
#pragma unroll
    for (int mi = 0; mi < 4; ++mi) {
      int base = (wc * 4 + mi) * 512 + lane * 8;
      wfh[mi] = *(const short8v*)&Wh[base];
      wfl[mi] = *(const short8v*)&Wl[base];
    }
#pragma unroll
    for (int ni = 0; ni < 4; ++ni) {
      int base = (wh * 4 + ni) * 512 + lane * 8;
      bfh[ni] = *(const short8v*)&Bh[base];
      bfl[ni] = *(const short8v*)&Bl[base];
    }
#pragma unroll
    for (int mi = 0; mi < 4; ++mi)
#pragma unroll
      for (int ni = 0; ni < 4; ++ni) {
        acc[mi][ni] = __builtin_amdgcn_mfma_f32_16x16x32_bf16(wfh[mi], bfh[ni], acc[mi][ni], 0, 0, 0);
        acc[mi][ni] = __builtin_amdgcn_mfma_f32_16x16x32_bf16(wfh[mi], bfl[ni], acc[mi][ni], 0, 0, 0);
        acc[mi][ni] = __builtin_amdgcn_mfma_f32_16x16x32_bf16(wfl[mi], bfh[ni], acc[mi][ni], 0, 0, 0);
      }
  }
#undef LOAD_TILE_PROJ

  float gsum[4][4];
#pragma unroll
  for (int mi = 0; mi < 4; ++mi)
#pragma unroll
    for (int r = 0; r < 4; ++r) gsum[mi][r] = 0.f;

#pragma unroll
  for (int mi = 0; mi < 4; ++mi) {
    const int c = c0 + wc * 64 + mi * 16 + (lane >> 4) * 4;
#pragma unroll
    for (int ni = 0; ni < 4; ++ni) {
      const int hwl = wh * 64 + ni * 16 + (lane & 15);
      const size_t base = ((size_t)b * 256 + c) * 4096 + hwp0 + hwl;
#pragma unroll
      for (int r = 0; r < 4; ++r) {
        const float val = acc[mi][ni][r] + bias[c + r];
        featsT[base + (size_t)r * 4096] = val;
        gsum[mi][r] += gelu_f(val);
      }
    }
  }
#pragma unroll
  for (int mi = 0; mi < 4; ++mi)
#pragma unroll
    for (int r = 0; r < 4; ++r) {
      float s = gsum[mi][r];
      s += __shfl_xor(s, 1);
      s += __shfl_xor(s, 2);
      s += __shfl_xor(s, 4);
      s += __shfl_xor(s, 8);
      gsum[mi][r] = s;
    }
  if ((lane & 15) == 0) {
#pragma unroll
    for (int mi = 0; mi < 4; ++mi)
#pragma unroll
      for (int r = 0; r < 4; ++r)
        pgelu[wh][wc * 64 + mi * 16 + (lane >> 4) * 4 + r] = gsum[mi][r];
  }
  __syncthreads();
  if (tid < 128) {
    const float s = pgelu[0][tid] + pgelu[1][tid] + pgelu[2][tid] + pgelu[3][tid];
    const int rbl = hwp0 >> 8;
    part[((size_t)b * 16 + rbl) * 256 + c0 + tid] = s;
  }
}

// ---------------------------------------------------------------------------
// Swapped-orientation MFMA GEMM for the final head.
// ---------------------------------------------------------------------------
__global__ __launch_bounds__(512) void gemm_mfma_final(
    const float* __restrict__ Act, const float* __restrict__ featsT,
    const float* __restrict__ av, const unsigned short* __restrict__ WhT,
    const unsigned short* __restrict__ WlT, const float* __restrict__ bias,
    float* __restrict__ out)
{
  __shared__ alignas(16) unsigned short Wh[4096];
  __shared__ alignas(16) unsigned short Wl[4096];
  __shared__ alignas(16) unsigned short Bh[8192];
  __shared__ alignas(16) unsigned short Bl[8192];
  __shared__ float avs[256];

  const int hw0 = blockIdx.x * 256;
  const int c0 = blockIdx.y * 128;
  const int b = hw0 >> 12;
  const int hwp0 = hw0 & 4095;
  const int tid = threadIdx.x;
  const int lane = tid & 63;
  const int wave = tid >> 6;
  const int wc = wave >> 2, wh = wave & 3;

  if (tid < 256) avs[tid] = av[b * 256 + tid];

  f32x4 acc[4][4];
#pragma unroll
  for (int mi = 0; mi < 4; ++mi)
#pragma unroll
    for (int ni = 0; ni < 4; ++ni) {
      f32x4 z = {0.f, 0.f, 0.f, 0.f};
      acc[mi][ni] = z;
    }

  float4 px[4], py[4];
  short8v pwh, pwl;

#define LOAD_TILE_FIN(k0_)                                                     \
  {                                                                            \
    _Pragma("unroll") for (int p = 0; p < 4; ++p) {                            \
      int f = p * 512 + tid;                                                   \
      int h = f >> 3, kq = f & 7;                                              \
      const float* bp = Act + (size_t)(hw0 + h) * 256 + (k0_) + kq * 4;        \
      px[p] = *(const float4*)bp;                                              \
      py[p] = *(const float4*)(bp + 128);                                      \
    }                                                                          \
    {                                                                          \
      int c = tid >> 2, ko = tid & 3;                                          \
      const size_t off = (size_t)(c0 + c) * 128 + (k0_) + ko * 8;              \
      pwh = *(const short8v*)(WhT + off);                                      \
      pwl = *(const short8v*)(WlT + off);                                      \
    }                                                                          \
  }

  LOAD_TILE_FIN(0);

  for (int ks = 0; ks < 4; ++ks) {
    const int k0 = ks * 32;
    __syncthreads();
    {
      int c = tid >> 2, ko = tid & 3;
      int e = (c >> 4) * 512 + ko * 128 + (c & 15) * 8;
      *(short8v*)&Wh[e] = pwh;
      *(short8v*)&Wl[e] = pwl;
    }
#pragma unroll
    for (int p = 0; p < 4; ++p) {
      int f = p * 512 + tid;
      int h = f >> 3, kq = f & 7;
      const float4 a0 = *(const float4*)(avs + k0 + kq * 4);
      const float4 a1 = *(const float4*)(avs + 128 + k0 + kq * 4);
      float fx[4];
      fx[0] = px[p].x * a0.x + py[p].x * a1.x;
      fx[1] = px[p].y * a0.y + py[p].y * a1.y;
      fx[2] = px[p].z * a0.z + py[p].z * a1.z;
      fx[3] = px[p].w * a0.w + py[p].w * a1.w;
      unsigned short hh[4], ll[4];
#pragma unroll
      for (int j = 0; j < 4; ++j) {
        hh[j] = f32_to_bf16_rne(fx[j]);
        ll[j] = f32_to_bf16_rne(fx[j] - bf16_hi_to_f32(hh[j]));
      }
      int e4 = (h >> 4) * 512 + (kq >> 1) * 128 + (h & 15) * 8 + (kq & 1) * 4;
      short4v hv = {(short)hh[0], (short)hh[1], (short)hh[2], (short)hh[3]};
      short4v lv = {(short)ll[0], (short)ll[1], (short)ll[2], (short)ll[3]};
      *(short4v*)&Bh[e4] = hv;
      *(short4v*)&Bl[e4] = lv;
    }
    __syncthreads();

    if (ks < 3) LOAD_TILE_FIN((ks + 1) * 32);

    short8v wfh[4], wfl[4], bfh[4], bfl[4];
#pragma unroll
    for (int mi = 0; mi < 4; ++mi) {
      int base = (wc * 4 + mi) * 512 + lane * 8;
      wfh[mi] = *(const short8v*)&Wh[base];
      wfl[mi] = *(const short8v*)&Wl[base];
    }
#pragma unroll
    for (int ni = 0; ni < 4; ++ni) {
      int base = (wh * 4 + ni) * 512 + lane * 8;
      bfh[ni] = *(const short8v*)&Bh[base];
      bfl[ni] = *(const short8v*)&Bl[base];
    }
#pragma unroll
    for (int mi = 0; mi < 4; ++mi)
#pragma unroll
      for (int ni = 0; ni < 4; ++ni) {
        acc[mi][ni] = __builtin_amdgcn_mfma_f32_16x16x32_bf16(wfh[mi], bfh[ni], acc[mi][ni], 0, 0, 0);
        acc[mi][ni] = __builtin_amdgcn_mfma_f32_16x16x32_bf16(wfh[mi], bfl[ni], acc[mi][ni], 0, 0, 0);
        acc[mi][ni] = __builtin_amdgcn_mfma_f32_16x16x32_bf16(wfl[mi], bfh[ni], acc[mi][ni], 0, 0, 0);
      }
  }
#undef LOAD_TILE_FIN

#pragma unroll
  for (int mi = 0; mi < 4; ++mi) {
    const int c = c0 + wc * 64 + mi * 16 + (lane >> 4) * 4;
#pragma unroll
    for (int ni = 0; ni < 4; ++ni) {
      const int hwl = wh * 64 + ni * 16 + (lane & 15);
      const size_t base = ((size_t)b * 256 + c) * 4096 + hwp0 + hwl;
#pragma unroll
      for (int r = 0; r < 4; ++r)
        out[base + (size_t)r * 4096] =
            acc[mi][ni][r] + bias[c + r] + featsT[base + (size_t)r * 4096];
    }
  }
}

// ---------------------------------------------------------------------------
// Windowed attention, chunked K/V staging (CHUNK = N/4, 4 chunks).
// One workgroup per (window, head), one thread per query row. Online softmax
// over sub-chunks of SUB=min(CHUNK,32). LDS vs round-6 baseline:
//   ws=16: 78.8KB -> ~20.6KB (~5 blocks/CU, VGPR-bound);
//   ws=8 :  19 KB -> ~5.1KB (HW workgroup cap ~16 blocks/CU).
// Staging map: rl=t>>2 (row), qc=t&3 (8-ch quarter) — exact bijection.
// Bias stored bf16 (err ~4e-5), region ids u8. IN-PLACE q output.
// ---------------------------------------------------------------------------
template <int WS, int SH, int GRP>
__global__ __launch_bounds__(WS * WS, 4) void attn_kernel(
    float* qio, const float* __restrict__ kvbuf, const float* __restrict__ rpb)
{
  constexpr int N = WS * WS;
  constexpr int CHUNK = N / 4;
  constexpr int SUB = (CHUNK < 32) ? CHUNK : 32;
  constexpr int NW = 64 / WS;
  constexpr int NBIAS = (2 * WS - 1) * (2 * WS - 1);
  constexpr int LOGWS = (WS == 8) ? 3 : 4;

  __shared__ float ks[CHUNK][36];
  __shared__ float vs[CHUNK][36];
  __shared__ unsigned short sbias[NBIAS];
  __shared__ unsigned char sreg[N];

  const int head = blockIdx.x & 3;
  const int win = blockIdx.x >> 2;
  const int b = win / (NW * NW);
  const int wl = win % (NW * NW);
  const int wi = wl / NW, wj = wl % NW;
  const int t = threadIdx.x;
  const int ti = t >> LOGWS, tj = t & (WS - 1);
  const int hr = wi * WS + ti, wr = wj * WS + tj;
  const int hg = (hr + SH) & 63, wg = (wr + SH) & 63;
  const int cb = GRP * 128 + head * 32;

  const size_t pos = ((size_t)b * 64 + hg) * 64 + wg;
  float* qp = qio + pos * 256 + cb;

  constexpr float scale = 0.17677669529663687f;  // 32^-0.5
  float qreg[32];
#pragma unroll
  for (int d4 = 0; d4 < 8; ++d4) {
    float4 qv = *(const float4*)(qp + d4 * 4);
    qreg[d4 * 4 + 0] = qv.x * scale; qreg[d4 * 4 + 1] = qv.y * scale;
    qreg[d4 * 4 + 2] = qv.z * scale; qreg[d4 * 4 + 3] = qv.w * scale;
  }
  for (int i = t; i < NBIAS; i += N) sbias[i] = f32_to_bf16_rne(rpb[i * 4 + head]);
  const int rrh = (hr < 64 - WS) ? 0 : ((hr < 64 - SH) ? 1 : 2);
  const int rrw = (wr < 64 - WS) ? 0 : ((wr < 64 - SH) ? 1 : 2);
  const int myreg = rrh * 3 + rrw;
  sreg[t] = (unsigned char)myreg;

  float oacc[32];
#pragma unroll
  for (int d = 0; d < 32; ++d) oacc[d] = 0.f;
  float mrun = -1e30f, lrun = 0.f;
  const int tbias = (ti + WS - 1) * (2 * WS - 1) + (tj + WS - 1);

  // 4 chunks of CHUNK keys; 2 barriers per chunk.
  for (int c = 0; c < 4; ++c) {
    __syncthreads();  // prev chunk consumed (c=0: sbias/sreg published)
    {
      const int rl = t >> 2;        // local key row 0..CHUNK-1
      const int qc = t & 3;         // 8-channel quarter
      const int m = c * CHUNK + rl;
      const int kmi = m >> LOGWS, kmj = m & (WS - 1);
      const int hk = (wi * WS + kmi + SH) & 63;
      const int wk = (wj * WS + kmj + SH) & 63;
      const float* kpm =
          kvbuf + (((size_t)b * 64 + hk) * 64 + wk) * 512 + cb + qc * 8;
      const float* vpm = kpm + 256;
#pragma unroll
      for (int d4 = 0; d4 < 2; ++d4) {
        *(float4*)&ks[rl][qc * 8 + d4 * 4] = *(const float4*)(kpm + d4 * 4);
        *(float4*)&vs[rl][qc * 8 + d4 * 4] = *(const float4*)(vpm + d4 * 4);
      }
    }
    __syncthreads();  // chunk staged

    for (int mc = 0; mc < CHUNK; mc += SUB) {
      float s[SUB];
#pragma unroll
      for (int mm = 0; mm < SUB; ++mm) {
        const int ml = mc + mm;            // row in LDS chunk
        const int mg = c * CHUNK + ml;     // global key index
        const float* kr = &ks[ml][0];
        float dot = 0.f;
#pragma unroll
        for (int d4 = 0; d4 < 8; ++d4) {
          float4 k4 = *(const float4*)(kr + d4 * 4);
          dot += qreg[d4 * 4 + 0] * k4.x + qreg[d4 * 4 + 1] * k4.y +
                 qreg[d4 * 4 + 2] * k4.z + qreg[d4 * 4 + 3] * k4.w;
        }
        const int kmi = mg >> LOGWS, kmj = mg & (WS - 1);
        const float bias =
            bf16_hi_to_f32(sbias[tbias - kmi * (2 * WS - 1) - kmj]);
        const float msk = (sreg[mg] == myreg) ? 0.f : -100.f;
        s[mm] = dot + bias + msk;
      }
      float mx = mrun;
#pragma unroll
      for (int mm = 0; mm < SUB; ++mm) mx = fmaxf(mx, s[mm]);
      const float corr = __expf(mrun - mx);
      lrun *= corr;
#pragma unroll
      for (int d = 0; d < 32; ++d) oacc[d] *= corr;
#pragma unroll
      for (int mm = 0; mm < SUB; ++mm) {
        const int ml = mc + mm;
        const float p = __expf(s[mm] - mx);
        lrun += p;
        const float* vr = &vs[ml][0];
#pragma unroll
        for (int d4 = 0; d4 < 8; ++d4) {
          float4 v4 = *(const float4*)(vr + d4 * 4);
          oacc[d4 * 4 + 0] += p * v4.x; oacc[d4 * 4 + 1] += p * v4.y;
          oacc[d4 * 4 + 2] += p * v4.z; oacc[d4 * 4 + 3] += p * v4.w;
        }
      }
      mrun = mx;
    }
  }

  const float inv = 1.f / lrun;
#pragma unroll
  for (int d4 = 0; d4 < 8; ++d4) {
    float4 o;
    o.x = oacc[d4 * 4 + 0] * inv; o.y = oacc[d4 * 4 + 1] * inv;
    o.z = oacc[d4 * 4 + 2] * inv; o.w = oacc[d4 * 4 + 3] * inv;
    *(float4*)(qp + d4 * 4) = o;
  }
}

// ---------------------------------------------------------------------------
// SK squeeze-excite MLP (tiny).
// ---------------------------------------------------------------------------
__global__ __launch_bounds__(256) void sk_small(
    const float* __restrict__ part, const float* __restrict__ f1w,
    const float* __restrict__ f1b, const float* __restrict__ f2w,
    const float* __restrict__ f2b, float* __restrict__ av)
{
  const int b = blockIdx.x;
  __shared__ float S[256];
  __shared__ float Z[64];
  __shared__ float Araw[256];
  const int tid = threadIdx.x;
  {
    float s = 0.f;
    for (int rb = 0; rb < 16; ++rb) s += part[((size_t)b * 16 + rb) * 256 + tid];
    S[tid] = s * (1.f / 4096.f);
  }
  __syncthreads();
  if (tid < 64) {
    float s = f1b[tid];
    for (int c = 0; c < 256; ++c) s += S[c] * f1w[c * 64 + tid];
    Z[tid] = gelu_f(s);
  }
  __syncthreads();
  {
    float s = f2b[tid];
    for (int j = 0; j < 64; ++j) s += Z[j] * f2w[j * 256 + tid];
    Araw[tid] = s;
  }
  __syncthreads();
  if (tid < 128) {
    float a0 = Araw[tid], a1 = Araw[128 + tid];
    float mx = fmaxf(a0, a1);
    float e0 = expf(a0 - mx), e1 = expf(a1 - mx);
    float inv = 1.f / (e0 + e1);
    av[b * 256 + tid] = e0 * inv;
    av[b * 256 + 128 + tid] = e1 * inv;
  }
}

// ---------------------------------------------------------------------------
extern "C" void kernel_launch(void* const* d_in, const int* in_sizes, int n_in,
                              void* d_out, int out_size, void* d_ws, size_t ws_size,
                              hipStream_t stream)
{
  (void)in_sizes; (void)n_in; (void)out_size;
  const float* x_q   = (const float*)d_in[0];
  const float* x_kv  = (const float*)d_in[1];
  const float* w_q   = (const float*)d_in[2];
  const float* b_q   = (const float*)d_in[3];
  const float* w_kv  = (const float*)d_in[4];
  const float* b_kv  = (const float*)d_in[5];
  const float* rpb0  = (const float*)d_in[6];
  const float* rpb1  = (const float*)d_in[7];
  const float* pw    = (const float*)d_in[8];
  const float* pb    = (const float*)d_in[9];
  const float* f1w   = (const float*)d_in[10];
  const float* f1b   = (const float*)d_in[11];
  const float* f2w   = (const float*)d_in[12];
  const float* f2b   = (const float*)d_in[13];
  const float* phw   = (const float*)d_in[14];
  const float* phb   = (const float*)d_in[15];
  float* out = (float*)d_out;

  float* ws = (float*)d_ws;
  float* qb  = ws;                      // 64 MiB; attention output IN-PLACE
  float* kvb = ws + 16777216;           // 128 MiB; featsT aliases after attn
  float* featsT = kvb;
  float* xatt = qb;

  // ws_size-adaptive tail (256B aligned): q/kv decomp weights (dead after
  // q/kv GEMMs; part+avb alias), then pw/phw decomp weights (live to end).
  const size_t tail_bytes = 1179648;
  uintptr_t tail_addr = ((uintptr_t)d_ws + ws_size - tail_bytes) & ~(uintptr_t)255;
  unsigned short* wqh = (unsigned short*)tail_addr;
  unsigned short* wql = wqh + 65536;
  unsigned short* wkh = wql + 65536;
  unsigned short* wkl = wkh + 131072;
  float* part = (float*)tail_addr;
  float* avb  = part + 65536;
  unsigned short* pwh = wkl + 131072;
  unsigned short* pwl = pwh + 65536;
  unsigned short* phh = pwl + 65536;
  unsigned short* phl = phh + 32768;

  decomp_w<<<dim3(4, 256), 64, 0, stream>>>(w_q, wqh, wql, 256, 256);
  decomp_w<<<dim3(8, 256), 64, 0, stream>>>(w_kv, wkh, wkl, 512, 256);
  decomp_w<<<dim3(4, 256), 64, 0, stream>>>(pw, pwh, pwl, 256, 256);
  decomp_w<<<dim3(4, 128), 64, 0, stream>>>(phw, phh, phl, 256, 128);
  gemm_mfma_bias<<<dim3(512, 1), 512, 0, stream>>>(x_q, wqh, wql, b_q, qb, 256);
  gemm_mfma_bias<<<dim3(512, 2), 512, 0, stream>>>(x_kv, wkh, wkl, b_kv, kvb, 512);
  attn_kernel<8, 4, 0><<<4096, 64, 0, stream>>>(qb, kvb, rpb0);
  attn_kernel<16, 8, 1><<<1024, 256, 0, stream>>>(qb, kvb, rpb1);
  gemm_mfma_proj<<<dim3(256, 2), 512, 0, stream>>>(xatt, pwh, pwl, pb, featsT, part);
  sk_small<<<16, 256, 0, stream>>>(part, f1w, f1b, f2w, f2b, avb);
  gemm_mfma_final<<<dim3(256, 2), 512, 0, stream>>>(xatt, featsT, avb, phh, phl, phb, out);
}